// Round 1
// baseline (1369.695 us; speedup 1.0000x reference)
//
#include <hip/hip_runtime.h>
#include <hip/hip_bf16.h>

#define NPTS 262144
#define DIM 256
#define NSB 8
#define NLBL 64
#define NSEG (NSB * NLBL)

// ---------------- Kernel 1: fused L2-normalize + segment accumulate ----------------
// One wave (64 lanes) per point; lane l holds dims [4l, 4l+4).
__global__ void k_norm_accum(const float* __restrict__ outp,
                             const int* __restrict__ labels,
                             const int* __restrict__ sbidx,
                             float* __restrict__ rnorm,
                             float* __restrict__ sums,
                             int* __restrict__ counts, int n) {
    int gtid = blockIdx.x * blockDim.x + threadIdx.x;
    int wave = gtid >> 6;
    int lane = threadIdx.x & 63;
    int nwaves = (gridDim.x * blockDim.x) >> 6;
    for (int p = wave; p < n; p += nwaves) {
        float4 v = *reinterpret_cast<const float4*>(outp + (size_t)p * DIM + lane * 4);
        float ss = v.x * v.x + v.y * v.y + v.z * v.z + v.w * v.w;
        #pragma unroll
        for (int m = 32; m >= 1; m >>= 1) ss += __shfl_xor(ss, m, 64);
        float rn = 1.0f / (sqrtf(ss) + 1e-8f);
        if (lane == 0) rnorm[p] = rn;
        int seg = sbidx[p] * NLBL + labels[p];
        float* s = sums + (size_t)seg * DIM + lane * 4;
        atomicAdd(s + 0, v.x * rn);
        atomicAdd(s + 1, v.y * rn);
        atomicAdd(s + 2, v.z * rn);
        atomicAdd(s + 3, v.w * rn);
        if (lane == 0) atomicAdd(counts + seg, 1);
    }
}

// ---------------- Kernel 2: finalize centroids + M per subbatch ----------------
__global__ void k_finalize(float* __restrict__ sums, const int* __restrict__ counts,
                           float* __restrict__ Mvals) {
    int seg = blockIdx.x;           // 512 blocks, 256 threads
    int c = counts[seg];
    float inv = 1.0f / fmaxf((float)c, 1.0f);
    sums[(size_t)seg * DIM + threadIdx.x] *= inv;
    if (threadIdx.x == 0 && c > 0) atomicAdd(&Mvals[seg >> 6], 1.0f);
}

// ---------------- Kernel 3: push term (pairwise centroid L1 dist) ----------------
// grid = 8 subbatches * 16 pair-chunks = 128 blocks, 256 threads (one pair/thread)
__global__ void k_push(const float* __restrict__ mus, const int* __restrict__ counts,
                       float* __restrict__ pushv) {
    __shared__ float lds[NLBL][DIM + 1];  // +1 pad -> bank stride 257
    int s = blockIdx.x >> 4;
    int chunk = blockIdx.x & 15;
    for (int i = threadIdx.x; i < NLBL * DIM; i += 256) {
        int r = i >> 8, d = i & 255;
        lds[r][d] = mus[((size_t)s * NLBL + r) * DIM + d];
    }
    __syncthreads();
    int pair = chunk * 256 + threadIdx.x;   // 0..4095
    int l1 = pair >> 6, l2 = pair & 63;
    float dist = 0.0f;
    #pragma unroll 8
    for (int d = 0; d < DIM; d++) dist += fabsf(lds[l1][d] - lds[l2][d]);
    float v = fmaxf(3.0f - dist, 0.0f);   // 2*DELTA_D = 3.0
    v = v * v;
    bool ok = (l1 != l2) && (counts[s * NLBL + l1] > 0) && (counts[s * NLBL + l2] > 0);
    v = ok ? v : 0.0f;
    #pragma unroll
    for (int m = 32; m >= 1; m >>= 1) v += __shfl_xor(v, m, 64);
    __shared__ float wsum[4];
    if ((threadIdx.x & 63) == 0) wsum[threadIdx.x >> 6] = v;
    __syncthreads();
    if (threadIdx.x == 0) atomicAdd(&pushv[s], wsum[0] + wsum[1] + wsum[2] + wsum[3]);
}

// ---------------- Kernel 4: pull term ----------------
__global__ void k_pull(const float* __restrict__ outp,
                       const int* __restrict__ labels,
                       const int* __restrict__ sbidx,
                       const float* __restrict__ rnorm,
                       const float* __restrict__ mus,
                       const int* __restrict__ counts,
                       const float* __restrict__ Mvals,
                       float* __restrict__ Lpull, int n) {
    __shared__ float lp[NSB];
    if (threadIdx.x < NSB) lp[threadIdx.x] = 0.0f;
    __syncthreads();
    int gtid = blockIdx.x * blockDim.x + threadIdx.x;
    int wave = gtid >> 6;
    int lane = threadIdx.x & 63;
    int nwaves = (gridDim.x * blockDim.x) >> 6;
    for (int p = wave; p < n; p += nwaves) {
        float4 v = *reinterpret_cast<const float4*>(outp + (size_t)p * DIM + lane * 4);
        float rn = rnorm[p];
        int s = sbidx[p];
        int seg = s * NLBL + labels[p];
        float4 m4 = *reinterpret_cast<const float4*>(mus + (size_t)seg * DIM + lane * 4);
        float d1 = fabsf(m4.x - v.x * rn) + fabsf(m4.y - v.y * rn) +
                   fabsf(m4.z - v.z * rn) + fabsf(m4.w - v.w * rn);
        #pragma unroll
        for (int m = 32; m >= 1; m >>= 1) d1 += __shfl_xor(d1, m, 64);
        if (lane == 0) {
            float t = fmaxf(d1 - 0.5f, 0.0f);   // DELTA_V = 0.5
            float pull = t * t;
            float denom = Mvals[s] * (float)counts[seg];
            atomicAdd(&lp[s], pull / denom);
        }
    }
    __syncthreads();
    if (threadIdx.x < NSB) atomicAdd(&Lpull[threadIdx.x], lp[threadIdx.x]);
}

// ---------------- Kernel 5: final combine ----------------
__global__ void k_final(const float* __restrict__ Lpull, const float* __restrict__ pushv,
                        const float* __restrict__ Mvals, float* __restrict__ outv, int n) {
    if (threadIdx.x == 0 && blockIdx.x == 0) {
        float loss = 0.0f;
        for (int s = 0; s < NSB; s++) {
            float M = Mvals[s];
            if (M > 1.0f) {
                loss += Lpull[s] + pushv[s] / fmaxf(M * (M - 1.0f), 1.0f);
            }
        }
        outv[0] = loss / (float)n;
    }
}

extern "C" void kernel_launch(void* const* d_in, const int* in_sizes, int n_in,
                              void* d_out, int out_size, void* d_ws, size_t ws_size,
                              hipStream_t stream) {
    const float* outp = (const float*)d_in[0];
    const int* labels = (const int*)d_in[1];
    const int* sbidx = (const int*)d_in[2];
    float* out = (float*)d_out;
    int n = in_sizes[1];

    // workspace layout
    float* rnorm = (float*)d_ws;                       // N floats
    float* sums = rnorm + NPTS;                        // 512*256 floats (becomes mus)
    int* counts = (int*)(sums + NSEG * DIM);           // 512 ints
    float* Mvals = (float*)(counts + NSEG);            // 8
    float* Lpull = Mvals + NSB;                        // 8
    float* pushv = Lpull + NSB;                        // 8

    size_t zero_bytes = (size_t)(NSEG * DIM + NSEG + 3 * NSB) * 4;
    hipMemsetAsync(sums, 0, zero_bytes, stream);

    k_norm_accum<<<8192, 256, 0, stream>>>(outp, labels, sbidx, rnorm, sums, counts, n);
    k_finalize<<<NSEG, DIM, 0, stream>>>(sums, counts, Mvals);
    k_push<<<NSB * 16, 256, 0, stream>>>(sums, counts, pushv);
    k_pull<<<8192, 256, 0, stream>>>(outp, labels, sbidx, rnorm, sums, counts, Mvals, Lpull, n);
    k_final<<<1, 64, 0, stream>>>(Lpull, pushv, Mvals, out, n);
}

// Round 2
// 226.120 us; speedup vs baseline: 6.0574x; 6.0574x over previous
//
#include <hip/hip_runtime.h>
#include <hip/hip_bf16.h>

#define DIM 256
#define NSB 8
#define NLBL 64
#define NSEG (NSB * NLBL)
#define BPS 4   // blocks per segment for accum/pull

// ---------------- k1: seg ids + histogram (LDS-aggregated) ----------------
__global__ void k_hist(const int* __restrict__ labels, const int* __restrict__ sbidx,
                       int* __restrict__ seg_out, int* __restrict__ counts, int n) {
    __shared__ int bins[NSEG];
    for (int i = threadIdx.x; i < NSEG; i += blockDim.x) bins[i] = 0;
    __syncthreads();
    int stride = gridDim.x * blockDim.x;
    for (int p = blockIdx.x * blockDim.x + threadIdx.x; p < n; p += stride) {
        int seg = sbidx[p] * NLBL + labels[p];
        seg_out[p] = seg;
        atomicAdd(&bins[seg], 1);
    }
    __syncthreads();
    for (int i = threadIdx.x; i < NSEG; i += blockDim.x)
        if (bins[i] > 0) atomicAdd(&counts[i], bins[i]);
}

// ---------------- k2: exclusive scan (one wave) + Mvals via ballot ----------------
__global__ void k_scan(const int* __restrict__ counts, int* __restrict__ offsets,
                       int* __restrict__ cursors, float* __restrict__ Mvals) {
    int lane = threadIdx.x;  // 64 threads
    int carry = 0;
    for (int c = 0; c < NSB; c++) {   // chunk c == subbatch c (64 labels each)
        int idx = c * 64 + lane;
        int v = counts[idx];
        int incl = v;
        #pragma unroll
        for (int m = 1; m < 64; m <<= 1) {
            int t = __shfl_up(incl, m, 64);
            if (lane >= m) incl += t;
        }
        int excl = carry + incl - v;
        offsets[idx] = excl;
        cursors[idx] = excl;
        carry += __shfl(incl, 63, 64);
        unsigned long long b = __ballot(v > 0);
        if (lane == 0) Mvals[c] = (float)__popcll(b);
    }
}

// ---------------- k3: scatter point indices into sorted order ----------------
__global__ void k_scatter(const int* __restrict__ seg, int* __restrict__ cursors,
                          int* __restrict__ sorted, int n) {
    int stride = gridDim.x * blockDim.x;
    for (int p = blockIdx.x * blockDim.x + threadIdx.x; p < n; p += stride) {
        int pos = atomicAdd(&cursors[seg[p]], 1);
        sorted[pos] = p;
    }
}

// ---------------- k4: gather rows per segment, normalize, accumulate (no atomics) ----------------
__global__ void k_accum(const float* __restrict__ outp, const int* __restrict__ sorted,
                        const int* __restrict__ offsets, const int* __restrict__ counts,
                        float* __restrict__ partials) {
    int seg = blockIdx.x >> 2;       // BPS = 4
    int part = blockIdx.x & 3;
    int base = offsets[seg], cnt = counts[seg];
    int chunk = (cnt + BPS - 1) / BPS;
    int lo = base + part * chunk;
    int hi = min(base + cnt, lo + chunk);
    int wv = threadIdx.x >> 6, lane = threadIdx.x & 63;
    float4 acc = {0.f, 0.f, 0.f, 0.f};
    int i = lo + wv;
    int nextp = (i < hi) ? sorted[i] : 0;
    for (; i < hi; i += 4) {
        int p = nextp;
        int ni = i + 4;
        nextp = (ni < hi) ? sorted[ni] : 0;   // prefetch next id over this row's work
        float4 v = *reinterpret_cast<const float4*>(outp + (size_t)p * DIM + lane * 4);
        float ss = v.x * v.x + v.y * v.y + v.z * v.z + v.w * v.w;
        #pragma unroll
        for (int m = 32; m >= 1; m >>= 1) ss += __shfl_xor(ss, m, 64);
        float rn = 1.0f / (sqrtf(ss) + 1e-8f);
        acc.x += v.x * rn; acc.y += v.y * rn; acc.z += v.z * rn; acc.w += v.w * rn;
    }
    __shared__ float pl[4][DIM];
    pl[wv][lane * 4 + 0] = acc.x;
    pl[wv][lane * 4 + 1] = acc.y;
    pl[wv][lane * 4 + 2] = acc.z;
    pl[wv][lane * 4 + 3] = acc.w;
    __syncthreads();
    int t = threadIdx.x;
    partials[(size_t)blockIdx.x * DIM + t] = pl[0][t] + pl[1][t] + pl[2][t] + pl[3][t];
}

// ---------------- k5: finalize centroids ----------------
__global__ void k_mu(const float* __restrict__ partials, const int* __restrict__ counts,
                     float* __restrict__ mus) {
    int seg = blockIdx.x, t = threadIdx.x;
    float s = 0.f;
    #pragma unroll
    for (int b = 0; b < BPS; b++) s += partials[((size_t)seg * BPS + b) * DIM + t];
    mus[(size_t)seg * DIM + t] = s / fmaxf((float)counts[seg], 1.0f);
}

// ---------------- k6: push term ----------------
__global__ void k_push(const float* __restrict__ mus, const int* __restrict__ counts,
                       float* __restrict__ pushv) {
    __shared__ float lds[NLBL][DIM + 1];
    int s = blockIdx.x >> 4;
    int chunk = blockIdx.x & 15;
    for (int i = threadIdx.x; i < NLBL * DIM; i += 256) {
        int r = i >> 8, d = i & 255;
        lds[r][d] = mus[((size_t)s * NLBL + r) * DIM + d];
    }
    __syncthreads();
    int pair = chunk * 256 + threadIdx.x;
    int l1 = pair >> 6, l2 = pair & 63;
    float dist = 0.0f;
    #pragma unroll 8
    for (int d = 0; d < DIM; d++) dist += fabsf(lds[l1][d] - lds[l2][d]);
    float v = fmaxf(3.0f - dist, 0.0f);   // 2*DELTA_D
    v = v * v;
    bool ok = (l1 != l2) && (counts[s * NLBL + l1] > 0) && (counts[s * NLBL + l2] > 0);
    v = ok ? v : 0.0f;
    #pragma unroll
    for (int m = 32; m >= 1; m >>= 1) v += __shfl_xor(v, m, 64);
    __shared__ float wsum[4];
    if ((threadIdx.x & 63) == 0) wsum[threadIdx.x >> 6] = v;
    __syncthreads();
    if (threadIdx.x == 0) atomicAdd(&pushv[s], wsum[0] + wsum[1] + wsum[2] + wsum[3]);
}

// ---------------- k7: pull term in sorted order (mu in registers, recompute norm) ----------------
__global__ void k_pull(const float* __restrict__ outp, const int* __restrict__ sorted,
                       const int* __restrict__ offsets, const int* __restrict__ counts,
                       const float* __restrict__ mus, const float* __restrict__ Mvals,
                       float* __restrict__ Lpull) {
    int seg = blockIdx.x >> 2;
    int part = blockIdx.x & 3;
    int sb = seg >> 6;
    int base = offsets[seg], cnt = counts[seg];
    if (cnt == 0) return;
    int chunk = (cnt + BPS - 1) / BPS;
    int lo = base + part * chunk;
    int hi = min(base + cnt, lo + chunk);
    int wv = threadIdx.x >> 6, lane = threadIdx.x & 63;
    float4 mu = *reinterpret_cast<const float4*>(mus + (size_t)seg * DIM + lane * 4);
    float psum = 0.f;
    int i = lo + wv;
    int nextp = (i < hi) ? sorted[i] : 0;
    for (; i < hi; i += 4) {
        int p = nextp;
        int ni = i + 4;
        nextp = (ni < hi) ? sorted[ni] : 0;
        float4 v = *reinterpret_cast<const float4*>(outp + (size_t)p * DIM + lane * 4);
        float ss = v.x * v.x + v.y * v.y + v.z * v.z + v.w * v.w;
        #pragma unroll
        for (int m = 32; m >= 1; m >>= 1) ss += __shfl_xor(ss, m, 64);
        float rn = 1.0f / (sqrtf(ss) + 1e-8f);
        float d1 = fabsf(mu.x - v.x * rn) + fabsf(mu.y - v.y * rn) +
                   fabsf(mu.z - v.z * rn) + fabsf(mu.w - v.w * rn);
        #pragma unroll
        for (int m = 32; m >= 1; m >>= 1) d1 += __shfl_xor(d1, m, 64);
        float t = fmaxf(d1 - 0.5f, 0.0f);   // DELTA_V
        psum += t * t;
    }
    __shared__ float wsum[4];
    if (lane == 0) wsum[wv] = psum;
    __syncthreads();
    if (threadIdx.x == 0) {
        float tot = wsum[0] + wsum[1] + wsum[2] + wsum[3];
        atomicAdd(&Lpull[sb], tot / (Mvals[sb] * (float)cnt));
    }
}

// ---------------- k8: final combine ----------------
__global__ void k_final(const float* __restrict__ Lpull, const float* __restrict__ pushv,
                        const float* __restrict__ Mvals, float* __restrict__ outv, int n) {
    if (threadIdx.x == 0 && blockIdx.x == 0) {
        float loss = 0.0f;
        for (int s = 0; s < NSB; s++) {
            float M = Mvals[s];
            if (M > 1.0f)
                loss += Lpull[s] + pushv[s] / fmaxf(M * (M - 1.0f), 1.0f);
        }
        outv[0] = loss / (float)n;
    }
}

extern "C" void kernel_launch(void* const* d_in, const int* in_sizes, int n_in,
                              void* d_out, int out_size, void* d_ws, size_t ws_size,
                              hipStream_t stream) {
    const float* outp = (const float*)d_in[0];
    const int* labels = (const int*)d_in[1];
    const int* sbidx = (const int*)d_in[2];
    float* out = (float*)d_out;
    int n = in_sizes[1];

    // workspace layout
    float* mus = (float*)d_ws;                          // 512*256
    float* partials = mus + (size_t)NSEG * DIM;         // 2048*256
    int* seg = (int*)(partials + (size_t)NSEG * BPS * DIM);  // N
    int* sorted = seg + n;                               // N
    int* counts = sorted + n;                            // 512
    float* Lpull = (float*)(counts + NSEG);              // 8
    float* pushv = Lpull + NSB;                          // 8
    int* offsets = (int*)(pushv + NSB);                  // 512
    int* cursors = offsets + NSEG;                       // 512
    float* Mvals = (float*)(cursors + NSEG);             // 8

    // zero: counts + Lpull + pushv (contiguous)
    hipMemsetAsync(counts, 0, (NSEG + 2 * NSB) * 4, stream);

    k_hist<<<256, 256, 0, stream>>>(labels, sbidx, seg, counts, n);
    k_scan<<<1, 64, 0, stream>>>(counts, offsets, cursors, Mvals);
    k_scatter<<<512, 256, 0, stream>>>(seg, cursors, sorted, n);
    k_accum<<<NSEG * BPS, 256, 0, stream>>>(outp, sorted, offsets, counts, partials);
    k_mu<<<NSEG, DIM, 0, stream>>>(partials, counts, mus);
    k_push<<<NSB * 16, 256, 0, stream>>>(mus, counts, pushv);
    k_pull<<<NSEG * BPS, 256, 0, stream>>>(outp, sorted, offsets, counts, mus, Mvals, Lpull);
    k_final<<<1, 64, 0, stream>>>(Lpull, pushv, Mvals, out, n);
}